// Round 3
// baseline (1979.794 us; speedup 1.0000x reference)
//
#include <hip/hip_runtime.h>
#include <math.h>

#define NT      1024
#define NPIX    16384
#define NSLICES 8
#define NMODES  4
#define OBJW    512

// ---- complex helpers -------------------------------------------------------
__device__ __forceinline__ float2 cmul(float2 a, float2 b) {
    return make_float2(fmaf(a.x, b.x, -a.y * b.y), fmaf(a.x, b.y, a.y * b.x));
}

// 4-bit reversal (constexpr -> folds to literals in unrolled loops)
__host__ __device__ constexpr int BR4(int p) {
    return ((p & 1) << 3) | ((p & 2) << 1) | ((p & 4) >> 1) | ((p & 8) >> 3);
}

// W16^k = exp(-2*pi*i*k/16): (cos, sin) tables
__device__ __constant__ float TWC16[8] = {
    1.0f, 0.923879533f, 0.707106781f, 0.382683432f,
    0.0f, -0.382683432f, -0.707106781f, -0.923879533f };
__device__ __constant__ float TWS16[8] = {
    0.0f, 0.382683432f, 0.707106781f, 0.923879533f,
    1.0f, 0.923879533f, 0.707106781f, 0.382683432f };
// cross-8 stage-A twiddle fA(c) = (c<4) ? 1 : W8^(c-4)
__device__ __constant__ float FA_RE[8] = {1,1,1,1, 1.0f,  0.707106781f,  0.0f, -0.707106781f};
__device__ __constant__ float FA_IM[8] = {0,0,0,0, 0.0f, -0.707106781f, -1.0f, -0.707106781f};

// ---- local 16-point FFT in registers ---------------------------------------
// Forward DIF: natural in; out v[p] = X[BR4(p)].
__device__ __forceinline__ void fft16_fwd(float2 v[16]) {
    #pragma unroll
    for (int s = 8; s >= 1; s >>= 1) {
        #pragma unroll
        for (int q = 0; q < 16; q += 2 * s) {
            #pragma unroll
            for (int j = 0; j < s; j++) {
                const int tw = j * (8 / s);
                float2 u = v[q + j], w = v[q + j + s];
                v[q + j] = make_float2(u.x + w.x, u.y + w.y);
                float dx = u.x - w.x, dy = u.y - w.y;
                v[q + j + s] = make_float2(fmaf(dx, TWC16[tw],  dy * TWS16[tw]),
                                           fmaf(dy, TWC16[tw], -dx * TWS16[tw]));
            }
        }
    }
}
// Inverse DIT (unnormalized): in v[p] = Y[BR4(p)]; out natural.
__device__ __forceinline__ void fft16_inv(float2 v[16]) {
    #pragma unroll
    for (int s = 1; s <= 8; s <<= 1) {
        #pragma unroll
        for (int q = 0; q < 16; q += 2 * s) {
            #pragma unroll
            for (int j = 0; j < s; j++) {
                const int tw = j * (8 / s);
                float2 u = v[q + j], w = v[q + j + s];
                float2 tv = make_float2(fmaf(w.x, TWC16[tw], -w.y * TWS16[tw]),
                                        fmaf(w.y, TWC16[tw],  w.x * TWS16[tw]));
                v[q + j]     = make_float2(u.x + tv.x, u.y + tv.y);
                v[q + j + s] = make_float2(u.x - tv.x, u.y - tv.y);
            }
        }
    }
}

// ---- cross-thread 8-point FFT over sub-index c (shfl_xor 4,2,1) ------------
// Forward DIF-8: in thread c holds n1=c; out thread c holds q=br3(c).
__device__ __forceinline__ void cross8_fwd(float2 v[16], int c, float2 fA) {
    const float sA = (c < 4) ? 1.0f : -1.0f;
    const float sB = (c & 2) ? -1.0f : 1.0f;
    const float sC = (c & 1) ? -1.0f : 1.0f;
    const bool rot3 = ((c & 3) == 3);
    #pragma unroll
    for (int p = 0; p < 16; p++) {
        float ox = __shfl_xor(v[p].x, 4), oy = __shfl_xor(v[p].y, 4);
        float ax = fmaf(sA, v[p].x, ox), ay = fmaf(sA, v[p].y, oy);
        float bx = fmaf(ax, fA.x, -ay * fA.y);
        float by = fmaf(ax, fA.y,  ay * fA.x);
        ox = __shfl_xor(bx, 2); oy = __shfl_xor(by, 2);
        float nx = fmaf(sB, bx, ox), ny = fmaf(sB, by, oy);
        float rx = rot3 ?  ny : nx;          // *(-i) for c&3==3
        float ry = rot3 ? -nx : ny;
        ox = __shfl_xor(rx, 1); oy = __shfl_xor(ry, 1);
        v[p].x = fmaf(sC, rx, ox); v[p].y = fmaf(sC, ry, oy);
    }
}
// Inverse DIT-8 (unnormalized): in thread c holds q=br3(c); out n1=c.
__device__ __forceinline__ void cross8_inv(float2 v[16], int c, float2 fA) {
    const float sA = (c < 4) ? 1.0f : -1.0f;
    const float sB = (c & 2) ? -1.0f : 1.0f;
    const float sC = (c & 1) ? -1.0f : 1.0f;
    const bool rot3 = ((c & 3) == 3);
    #pragma unroll
    for (int p = 0; p < 16; p++) {
        float ox = __shfl_xor(v[p].x, 1), oy = __shfl_xor(v[p].y, 1);
        float nx = fmaf(sC, v[p].x, ox), ny = fmaf(sC, v[p].y, oy);
        float rx = rot3 ? -ny : nx;          // *(+i) for c&3==3
        float ry = rot3 ?  nx : ny;
        ox = __shfl_xor(rx, 2); oy = __shfl_xor(ry, 2);
        float bx = fmaf(sB, rx, ox), by = fmaf(sB, ry, oy);
        float ax = fmaf(bx, fA.x,  by * fA.y);   // * conj(fA)
        float ay = fmaf(by, fA.x, -bx * fA.y);
        ox = __shfl_xor(ax, 4); oy = __shfl_xor(ay, 4);
        v[p].x = fmaf(sA, ax, ox); v[p].y = fmaf(sA, ay, oy);
    }
}

// ---- full 128-point pass ---------------------------------------------------
// Reg i holds element (c + 8i); after fwd, reg p holds k = BR4(p) + 16*br3(c).
__device__ __forceinline__ void pass_fwd(float2 v[16], int c, float2 fA,
                                         const float2* t128) {
    fft16_fwd(v);
    #pragma unroll
    for (int p = 0; p < 16; p++)
        v[p] = cmul(v[p], t128[c * BR4(p)]);
    cross8_fwd(v, c, fA);
}
__device__ __forceinline__ void pass_inv(float2 v[16], int c, float2 fA,
                                         const float2* t128) {
    cross8_inv(v, c, fA);
    #pragma unroll
    for (int p = 0; p < 16; p++) {
        float2 w = t128[c * BR4(p)];
        v[p] = cmul(v[p], make_float2(w.x, -w.y));
    }
    fft16_inv(v);
}

// XOR swizzle for T1 buffer ([kw][r], no padding): col' = col ^ sw1(row)
__device__ __forceinline__ int sw1(int row) {
    return ((row ^ (row >> 4)) & 1) << 3;
}

// ---- main kernel: one block (1024 thr) per scan position -------------------
__global__ void __launch_bounds__(NT, 4)
multislice_kernel(const float* __restrict__ probe_re,
                  const float* __restrict__ probe_im,
                  const float* __restrict__ obj_re,
                  const float* __restrict__ obj_im,
                  const int*   __restrict__ positions,
                  float*       __restrict__ out)
{
    __shared__ float2 LT[NPIX];     // 131072 B swizzled transpose buffer
    __shared__ float2 t128[128];    // W128^i
    __shared__ float2 pyt[128];     // prop y-factor * (1/16384)

    const int t  = threadIdx.x;
    const int g  = t >> 3;                        // row / column-index [0,128)
    const int c  = t & 7;                         // sub-index in 128-FFT
    const int rc = ((c & 1) << 2) | (c & 2) | ((c & 4) >> 2);   // br3(c)
    const int n  = blockIdx.x;
    const int Y0 = positions[2 * n];
    const int X0 = positions[2 * n + 1];

    if (t < 128) {
        float ang = -2.0f * 3.14159265358979323846f * (float)t / 128.0f;
        float s, cc; __sincosf(ang, &s, &cc);
        t128[t] = make_float2(cc, s);
        float fy = (float)(t < 64 ? t : t - 128) * (1.0f / 25.6f);
        float ph = -0.15707963267948966f * fy * fy;
        float ps, pcs; __sincosf(ph, &ps, &pcs);
        pyt[t] = make_float2(pcs * (1.0f / 16384.0f), ps * (1.0f / 16384.0f));
    }
    const float2 fA = make_float2(FA_RE[c], FA_IM[c]);
    float fx = (float)(g < 64 ? g : g - 128) * (1.0f / 25.6f);
    float phx = -0.15707963267948966f * fx * fx;
    float pxs, pxc; __sincosf(phx, &pxs, &pxc);
    const float2 px = make_float2(pxc, pxs);
    __syncthreads();

    // combined propagator, C-state layout: pc[p] for (kh=BR4(p)+16rc, kw=g)
    float2 pc[16];
    #pragma unroll
    for (int p = 0; p < 16; p++)
        pc[p] = cmul(pyt[BR4(p) + 16 * rc], px);

    float acc[16];
    #pragma unroll
    for (int p = 0; p < 16; p++) acc[p] = 0.0f;

    float2 v[16];

    for (int m = 0; m < NMODES; m++) {
        __syncthreads();   // protect LT reuse across modes
        #pragma unroll
        for (int i = 0; i < 16; i++) {           // ex = probe[m]*patch(slice0)
            int w  = c + 8 * i;
            int pi = m * NPIX + g * 128 + w;
            float2 pr = make_float2(probe_re[pi], probe_im[pi]);
            int oi = (Y0 + g) * OBJW + X0 + w;
            float2 ob = make_float2(obj_re[oi], obj_im[oi]);
            v[i] = cmul(pr, ob);
        }

        for (int s = 1; s < NSLICES; s++) {
            pass_fwd(v, c, fA, t128);            // Fw
            #pragma unroll                       // T1 write [kw][r=g]
            for (int p = 0; p < 16; p++) {
                int kw = BR4(p) + 16 * rc;
                LT[kw * 128 + (g ^ sw1(kw))] = v[p];
            }
            __syncthreads();
            #pragma unroll                       // T1 read -> C-state
            for (int i = 0; i < 16; i++)
                v[i] = LT[g * 128 + ((c + 8 * i) ^ sw1(g))];
            __syncthreads();
            pass_fwd(v, c, fA, t128);            // Fh
            #pragma unroll                       // * prop (registers)
            for (int p = 0; p < 16; p++)
                v[p] = cmul(v[p], pc[p]);
            pass_inv(v, c, fA, t128);            // iFh
            #pragma unroll                       // T2 write [r][kw=g]
            for (int i = 0; i < 16; i++) {
                int r = c + 8 * i;
                int col = g ^ ((r & 7) << 1) ^ ((g >> 4) & 1);
                LT[r * 128 + col] = v[i];
            }
            __syncthreads();
            #pragma unroll                       // T2 read -> R-state(perm)
            for (int p = 0; p < 16; p++) {
                int kw = BR4(p) + 16 * rc;
                int col = kw ^ ((g & 7) << 1) ^ ((kw >> 4) & 1);
                v[p] = LT[g * 128 + col];
            }
            __syncthreads();
            pass_inv(v, c, fA, t128);            // iFw
            #pragma unroll                       // * patch(slice s)
            for (int i = 0; i < 16; i++) {
                int w  = c + 8 * i;
                int oi = (s * OBJW + Y0 + g) * OBJW + X0 + w;
                float2 ob = make_float2(obj_re[oi], obj_im[oi]);
                v[i] = cmul(v[i], ob);
            }
        }

        // final FFT2: Fw, T1, Fh, accumulate |.|^2
        pass_fwd(v, c, fA, t128);
        #pragma unroll
        for (int p = 0; p < 16; p++) {
            int kw = BR4(p) + 16 * rc;
            LT[kw * 128 + (g ^ sw1(kw))] = v[p];
        }
        __syncthreads();
        #pragma unroll
        for (int i = 0; i < 16; i++)
            v[i] = LT[g * 128 + ((c + 8 * i) ^ sw1(g))];
        pass_fwd(v, c, fA, t128);
        #pragma unroll
        for (int p = 0; p < 16; p++)
            acc[p] += v[p].x * v[p].x + v[p].y * v[p].y;
    }

    // store with fftshift: (kh,kw) -> (kh^64, kw^64); kh=BR4(p)+16rc, kw=g
    const long long base = (long long)n * NPIX;
    #pragma unroll
    for (int p = 0; p < 16; p++) {
        int kh = BR4(p) + 16 * rc;
        out[base + (long long)(((kh ^ 64) << 7) + (g ^ 64))] = acc[p];
    }
}

extern "C" void kernel_launch(void* const* d_in, const int* in_sizes, int n_in,
                              void* d_out, int out_size, void* d_ws, size_t ws_size,
                              hipStream_t stream) {
    const float* probe_re = (const float*)d_in[0];
    const float* probe_im = (const float*)d_in[1];
    const float* obj_re   = (const float*)d_in[2];
    const float* obj_im   = (const float*)d_in[3];
    const int*   pos      = (const int*)d_in[4];
    float* out = (float*)d_out;

    const int N = out_size / NPIX;   // 512 positions
    multislice_kernel<<<dim3(N), dim3(NT), 0, stream>>>(
        probe_re, probe_im, obj_re, obj_im, pos, out);
}

// Round 4
// 1976.872 us; speedup vs baseline: 1.0015x; 1.0015x over previous
//
#include <hip/hip_runtime.h>
#include <math.h>

#define NT      1024
#define NPIX    16384
#define NSLICES 8
#define NMODES  4
#define OBJW    512

// ---- complex helpers -------------------------------------------------------
__device__ __forceinline__ float2 cmul(float2 a, float2 b) {
    return make_float2(fmaf(a.x, b.x, -a.y * b.y), fmaf(a.x, b.y, a.y * b.x));
}

// 4-bit reversal (constexpr -> folds to literals in unrolled loops)
__host__ __device__ constexpr int BR4(int p) {
    return ((p & 1) << 3) | ((p & 2) << 1) | ((p & 4) >> 1) | ((p & 8) >> 3);
}

// W16^k = exp(-2*pi*i*k/16): (cos, sin) tables
__device__ __constant__ float TWC16[8] = {
    1.0f, 0.923879533f, 0.707106781f, 0.382683432f,
    0.0f, -0.382683432f, -0.707106781f, -0.923879533f };
__device__ __constant__ float TWS16[8] = {
    0.0f, 0.382683432f, 0.707106781f, 0.923879533f,
    1.0f, 0.923879533f, 0.707106781f, 0.382683432f };
// cross-8 stage-A twiddle fA(c) = (c<4) ? 1 : W8^(c-4)
__device__ __constant__ float FA_RE[8] = {1,1,1,1, 1.0f,  0.707106781f,  0.0f, -0.707106781f};
__device__ __constant__ float FA_IM[8] = {0,0,0,0, 0.0f, -0.707106781f, -1.0f, -0.707106781f};

// ---- local 16-point FFT in registers ---------------------------------------
// Forward DIF: natural in; out v[p] = X[BR4(p)].
__device__ __forceinline__ void fft16_fwd(float2 v[16]) {
    #pragma unroll
    for (int s = 8; s >= 1; s >>= 1) {
        #pragma unroll
        for (int q = 0; q < 16; q += 2 * s) {
            #pragma unroll
            for (int j = 0; j < s; j++) {
                const int tw = j * (8 / s);
                float2 u = v[q + j], w = v[q + j + s];
                v[q + j] = make_float2(u.x + w.x, u.y + w.y);
                float dx = u.x - w.x, dy = u.y - w.y;
                v[q + j + s] = make_float2(fmaf(dx, TWC16[tw],  dy * TWS16[tw]),
                                           fmaf(dy, TWC16[tw], -dx * TWS16[tw]));
            }
        }
    }
}
// Inverse DIT (unnormalized): in v[p] = Y[BR4(p)]; out natural.
__device__ __forceinline__ void fft16_inv(float2 v[16]) {
    #pragma unroll
    for (int s = 1; s <= 8; s <<= 1) {
        #pragma unroll
        for (int q = 0; q < 16; q += 2 * s) {
            #pragma unroll
            for (int j = 0; j < s; j++) {
                const int tw = j * (8 / s);
                float2 u = v[q + j], w = v[q + j + s];
                float2 tv = make_float2(fmaf(w.x, TWC16[tw], -w.y * TWS16[tw]),
                                        fmaf(w.y, TWC16[tw],  w.x * TWS16[tw]));
                v[q + j]     = make_float2(u.x + tv.x, u.y + tv.y);
                v[q + j + s] = make_float2(u.x - tv.x, u.y - tv.y);
            }
        }
    }
}

// ---- cross-thread 8-point FFT over sub-index c (shfl_xor 4,2,1) ------------
// Forward DIF-8: in thread c holds n1=c; out thread c holds q=br3(c).
__device__ __forceinline__ void cross8_fwd(float2 v[16], int c, float2 fA) {
    const float sA = (c < 4) ? 1.0f : -1.0f;
    const float sB = (c & 2) ? -1.0f : 1.0f;
    const float sC = (c & 1) ? -1.0f : 1.0f;
    const bool rot3 = ((c & 3) == 3);
    #pragma unroll
    for (int p = 0; p < 16; p++) {
        float ox = __shfl_xor(v[p].x, 4), oy = __shfl_xor(v[p].y, 4);
        float ax = fmaf(sA, v[p].x, ox), ay = fmaf(sA, v[p].y, oy);
        float bx = fmaf(ax, fA.x, -ay * fA.y);
        float by = fmaf(ax, fA.y,  ay * fA.x);
        ox = __shfl_xor(bx, 2); oy = __shfl_xor(by, 2);
        float nx = fmaf(sB, bx, ox), ny = fmaf(sB, by, oy);
        float rx = rot3 ?  ny : nx;          // *(-i) for c&3==3
        float ry = rot3 ? -nx : ny;
        ox = __shfl_xor(rx, 1); oy = __shfl_xor(ry, 1);
        v[p].x = fmaf(sC, rx, ox); v[p].y = fmaf(sC, ry, oy);
    }
}
// Inverse DIT-8 (unnormalized): in thread c holds q=br3(c); out n1=c.
__device__ __forceinline__ void cross8_inv(float2 v[16], int c, float2 fA) {
    const float sA = (c < 4) ? 1.0f : -1.0f;
    const float sB = (c & 2) ? -1.0f : 1.0f;
    const float sC = (c & 1) ? -1.0f : 1.0f;
    const bool rot3 = ((c & 3) == 3);
    #pragma unroll
    for (int p = 0; p < 16; p++) {
        float ox = __shfl_xor(v[p].x, 1), oy = __shfl_xor(v[p].y, 1);
        float nx = fmaf(sC, v[p].x, ox), ny = fmaf(sC, v[p].y, oy);
        float rx = rot3 ? -ny : nx;          // *(+i) for c&3==3
        float ry = rot3 ?  nx : ny;
        ox = __shfl_xor(rx, 2); oy = __shfl_xor(ry, 2);
        float bx = fmaf(sB, rx, ox), by = fmaf(sB, ry, oy);
        float ax = fmaf(bx, fA.x,  by * fA.y);   // * conj(fA)
        float ay = fmaf(by, fA.x, -bx * fA.y);
        ox = __shfl_xor(ax, 4); oy = __shfl_xor(ay, 4);
        v[p].x = fmaf(sA, ax, ox); v[p].y = fmaf(sA, ay, oy);
    }
}

// ---- full 128-point pass ---------------------------------------------------
// Reg i holds element (c + 8i); after fwd, reg p holds k = BR4(p) + 16*br3(c).
__device__ __forceinline__ void pass_fwd(float2 v[16], int c, float2 fA,
                                         const float2* t128) {
    fft16_fwd(v);
    #pragma unroll
    for (int p = 0; p < 16; p++)
        v[p] = cmul(v[p], t128[c * BR4(p)]);
    cross8_fwd(v, c, fA);
}
__device__ __forceinline__ void pass_inv(float2 v[16], int c, float2 fA,
                                         const float2* t128) {
    cross8_inv(v, c, fA);
    #pragma unroll
    for (int p = 0; p < 16; p++) {
        float2 w = t128[c * BR4(p)];
        v[p] = cmul(v[p], make_float2(w.x, -w.y));
    }
    fft16_inv(v);
}

// XOR swizzle for T1 buffer ([kw][r], no padding): col' = col ^ sw1(row)
__device__ __forceinline__ int sw1(int row) {
    return ((row ^ (row >> 4)) & 1) << 3;
}

// ---- main kernel: one block (1024 thr) per scan position -------------------
// amdgpu_waves_per_eu(4,4): pin EXACTLY 4 waves/EU (16 waves/CU = the 1
// block/CU the 130KB LDS allows anyway). Without the max, the round-3
// allocator targeted 8 waves/EU (64 VGPR) and spilled pc/acc to scratch:
// FETCH 587MB->2.75GB, dur 1684->1980us.
__global__ void __launch_bounds__(NT, 4)
__attribute__((amdgpu_waves_per_eu(4, 4)))
multislice_kernel(const float* __restrict__ probe_re,
                  const float* __restrict__ probe_im,
                  const float* __restrict__ obj_re,
                  const float* __restrict__ obj_im,
                  const int*   __restrict__ positions,
                  float*       __restrict__ out)
{
    __shared__ float2 LT[NPIX];     // 131072 B swizzled transpose buffer
    __shared__ float2 t128[128];    // W128^i
    __shared__ float2 pyt[128];     // prop y-factor * (1/16384)

    const int t  = threadIdx.x;
    const int g  = t >> 3;                        // row / column-index [0,128)
    const int c  = t & 7;                         // sub-index in 128-FFT
    const int rc = ((c & 1) << 2) | (c & 2) | ((c & 4) >> 2);   // br3(c)
    const int n  = blockIdx.x;
    const int Y0 = positions[2 * n];
    const int X0 = positions[2 * n + 1];

    if (t < 128) {
        float ang = -2.0f * 3.14159265358979323846f * (float)t / 128.0f;
        float s, cc; __sincosf(ang, &s, &cc);
        t128[t] = make_float2(cc, s);
        float fy = (float)(t < 64 ? t : t - 128) * (1.0f / 25.6f);
        float ph = -0.15707963267948966f * fy * fy;
        float ps, pcs; __sincosf(ph, &ps, &pcs);
        pyt[t] = make_float2(pcs * (1.0f / 16384.0f), ps * (1.0f / 16384.0f));
    }
    const float2 fA = make_float2(FA_RE[c], FA_IM[c]);
    float fx = (float)(g < 64 ? g : g - 128) * (1.0f / 25.6f);
    float phx = -0.15707963267948966f * fx * fx;
    float pxs, pxc; __sincosf(phx, &pxs, &pxc);
    const float2 px = make_float2(pxc, pxs);
    __syncthreads();

    // combined propagator, C-state layout: pc[p] for (kh=BR4(p)+16rc, kw=g)
    float2 pc[16];
    #pragma unroll
    for (int p = 0; p < 16; p++)
        pc[p] = cmul(pyt[BR4(p) + 16 * rc], px);

    float acc[16];
    #pragma unroll
    for (int p = 0; p < 16; p++) acc[p] = 0.0f;

    float2 v[16];

    for (int m = 0; m < NMODES; m++) {
        __syncthreads();   // protect LT reuse across modes
        #pragma unroll
        for (int i = 0; i < 16; i++) {           // ex = probe[m]*patch(slice0)
            int w  = c + 8 * i;
            int pi = m * NPIX + g * 128 + w;
            float2 pr = make_float2(probe_re[pi], probe_im[pi]);
            int oi = (Y0 + g) * OBJW + X0 + w;
            float2 ob = make_float2(obj_re[oi], obj_im[oi]);
            v[i] = cmul(pr, ob);
        }

        for (int s = 1; s < NSLICES; s++) {
            pass_fwd(v, c, fA, t128);            // Fw
            #pragma unroll                       // T1 write [kw][r=g]
            for (int p = 0; p < 16; p++) {
                int kw = BR4(p) + 16 * rc;
                LT[kw * 128 + (g ^ sw1(kw))] = v[p];
            }
            __syncthreads();
            #pragma unroll                       // T1 read -> C-state
            for (int i = 0; i < 16; i++)
                v[i] = LT[g * 128 + ((c + 8 * i) ^ sw1(g))];
            __syncthreads();
            pass_fwd(v, c, fA, t128);            // Fh
            #pragma unroll                       // * prop (registers)
            for (int p = 0; p < 16; p++)
                v[p] = cmul(v[p], pc[p]);
            pass_inv(v, c, fA, t128);            // iFh
            #pragma unroll                       // T2 write [r][kw=g]
            for (int i = 0; i < 16; i++) {
                int r = c + 8 * i;
                int col = g ^ ((r & 7) << 1) ^ ((g >> 4) & 1);
                LT[r * 128 + col] = v[i];
            }
            __syncthreads();
            #pragma unroll                       // T2 read -> R-state(perm)
            for (int p = 0; p < 16; p++) {
                int kw = BR4(p) + 16 * rc;
                int col = kw ^ ((g & 7) << 1) ^ ((kw >> 4) & 1);
                v[p] = LT[g * 128 + col];
            }
            __syncthreads();
            pass_inv(v, c, fA, t128);            // iFw
            #pragma unroll                       // * patch(slice s)
            for (int i = 0; i < 16; i++) {
                int w  = c + 8 * i;
                int oi = (s * OBJW + Y0 + g) * OBJW + X0 + w;
                float2 ob = make_float2(obj_re[oi], obj_im[oi]);
                v[i] = cmul(v[i], ob);
            }
        }

        // final FFT2: Fw, T1, Fh, accumulate |.|^2
        pass_fwd(v, c, fA, t128);
        #pragma unroll
        for (int p = 0; p < 16; p++) {
            int kw = BR4(p) + 16 * rc;
            LT[kw * 128 + (g ^ sw1(kw))] = v[p];
        }
        __syncthreads();
        #pragma unroll
        for (int i = 0; i < 16; i++)
            v[i] = LT[g * 128 + ((c + 8 * i) ^ sw1(g))];
        pass_fwd(v, c, fA, t128);
        #pragma unroll
        for (int p = 0; p < 16; p++)
            acc[p] += v[p].x * v[p].x + v[p].y * v[p].y;
    }

    // store with fftshift: (kh,kw) -> (kh^64, kw^64); kh=BR4(p)+16rc, kw=g
    const long long base = (long long)n * NPIX;
    #pragma unroll
    for (int p = 0; p < 16; p++) {
        int kh = BR4(p) + 16 * rc;
        out[base + (long long)(((kh ^ 64) << 7) + (g ^ 64))] = acc[p];
    }
}

extern "C" void kernel_launch(void* const* d_in, const int* in_sizes, int n_in,
                              void* d_out, int out_size, void* d_ws, size_t ws_size,
                              hipStream_t stream) {
    const float* probe_re = (const float*)d_in[0];
    const float* probe_im = (const float*)d_in[1];
    const float* obj_re   = (const float*)d_in[2];
    const float* obj_im   = (const float*)d_in[3];
    const int*   pos      = (const int*)d_in[4];
    float* out = (float*)d_out;

    const int N = out_size / NPIX;   // 512 positions
    multislice_kernel<<<dim3(N), dim3(NT), 0, stream>>>(
        probe_re, probe_im, obj_re, obj_im, pos, out);
}

// Round 5
// 1806.817 us; speedup vs baseline: 1.0957x; 1.0941x over previous
//
#include <hip/hip_runtime.h>
#include <math.h>

#define NT      1024
#define NPIX    16384
#define NSLICES 8
#define NMODES  4
#define OBJW    512

// ---- complex helpers -------------------------------------------------------
__device__ __forceinline__ float2 cmul(float2 a, float2 b) {
    return make_float2(fmaf(a.x, b.x, -a.y * b.y), fmaf(a.x, b.y, a.y * b.x));
}

// 4-bit reversal (constexpr -> folds to literals in unrolled loops)
__host__ __device__ constexpr int BR4(int p) {
    return ((p & 1) << 3) | ((p & 2) << 1) | ((p & 4) >> 1) | ((p & 8) >> 3);
}

// W16^k = exp(-2*pi*i*k/16): (cos, sin) tables
__device__ __constant__ float TWC16[8] = {
    1.0f, 0.923879533f, 0.707106781f, 0.382683432f,
    0.0f, -0.382683432f, -0.707106781f, -0.923879533f };
__device__ __constant__ float TWS16[8] = {
    0.0f, 0.382683432f, 0.707106781f, 0.923879533f,
    1.0f, 0.923879533f, 0.707106781f, 0.382683432f };
// cross-8 stage-A twiddle fA(c) = (c<4) ? 1 : W8^(c-4)
__device__ __constant__ float FA_RE[8] = {1,1,1,1, 1.0f,  0.707106781f,  0.0f, -0.707106781f};
__device__ __constant__ float FA_IM[8] = {0,0,0,0, 0.0f, -0.707106781f, -1.0f, -0.707106781f};

// ---- local 16-point FFT in registers ---------------------------------------
__device__ __forceinline__ void fft16_fwd(float2 v[16]) {
    #pragma unroll
    for (int s = 8; s >= 1; s >>= 1) {
        #pragma unroll
        for (int q = 0; q < 16; q += 2 * s) {
            #pragma unroll
            for (int j = 0; j < s; j++) {
                const int tw = j * (8 / s);
                float2 u = v[q + j], w = v[q + j + s];
                v[q + j] = make_float2(u.x + w.x, u.y + w.y);
                float dx = u.x - w.x, dy = u.y - w.y;
                v[q + j + s] = make_float2(fmaf(dx, TWC16[tw],  dy * TWS16[tw]),
                                           fmaf(dy, TWC16[tw], -dx * TWS16[tw]));
            }
        }
    }
}
__device__ __forceinline__ void fft16_inv(float2 v[16]) {
    #pragma unroll
    for (int s = 1; s <= 8; s <<= 1) {
        #pragma unroll
        for (int q = 0; q < 16; q += 2 * s) {
            #pragma unroll
            for (int j = 0; j < s; j++) {
                const int tw = j * (8 / s);
                float2 u = v[q + j], w = v[q + j + s];
                float2 tv = make_float2(fmaf(w.x, TWC16[tw], -w.y * TWS16[tw]),
                                        fmaf(w.y, TWC16[tw],  w.x * TWS16[tw]));
                v[q + j]     = make_float2(u.x + tv.x, u.y + tv.y);
                v[q + j + s] = make_float2(u.x - tv.x, u.y - tv.y);
            }
        }
    }
}

// ---- cross-thread 8-point FFT over sub-index c (shfl_xor 4,2,1) ------------
__device__ __forceinline__ void cross8_fwd(float2 v[16], int c, float2 fA) {
    const float sA = (c < 4) ? 1.0f : -1.0f;
    const float sB = (c & 2) ? -1.0f : 1.0f;
    const float sC = (c & 1) ? -1.0f : 1.0f;
    const bool rot3 = ((c & 3) == 3);
    #pragma unroll
    for (int p = 0; p < 16; p++) {
        float ox = __shfl_xor(v[p].x, 4), oy = __shfl_xor(v[p].y, 4);
        float ax = fmaf(sA, v[p].x, ox), ay = fmaf(sA, v[p].y, oy);
        float bx = fmaf(ax, fA.x, -ay * fA.y);
        float by = fmaf(ax, fA.y,  ay * fA.x);
        ox = __shfl_xor(bx, 2); oy = __shfl_xor(by, 2);
        float nx = fmaf(sB, bx, ox), ny = fmaf(sB, by, oy);
        float rx = rot3 ?  ny : nx;          // *(-i) for c&3==3
        float ry = rot3 ? -nx : ny;
        ox = __shfl_xor(rx, 1); oy = __shfl_xor(ry, 1);
        v[p].x = fmaf(sC, rx, ox); v[p].y = fmaf(sC, ry, oy);
    }
}
__device__ __forceinline__ void cross8_inv(float2 v[16], int c, float2 fA) {
    const float sA = (c < 4) ? 1.0f : -1.0f;
    const float sB = (c & 2) ? -1.0f : 1.0f;
    const float sC = (c & 1) ? -1.0f : 1.0f;
    const bool rot3 = ((c & 3) == 3);
    #pragma unroll
    for (int p = 0; p < 16; p++) {
        float ox = __shfl_xor(v[p].x, 1), oy = __shfl_xor(v[p].y, 1);
        float nx = fmaf(sC, v[p].x, ox), ny = fmaf(sC, v[p].y, oy);
        float rx = rot3 ? -ny : nx;          // *(+i) for c&3==3
        float ry = rot3 ?  nx : ny;
        ox = __shfl_xor(rx, 2); oy = __shfl_xor(ry, 2);
        float bx = fmaf(sB, rx, ox), by = fmaf(sB, ry, oy);
        float ax = fmaf(bx, fA.x,  by * fA.y);   // * conj(fA)
        float ay = fmaf(by, fA.x, -bx * fA.y);
        ox = __shfl_xor(ax, 4); oy = __shfl_xor(ay, 4);
        v[p].x = fmaf(sA, ax, ox); v[p].y = fmaf(sA, ay, oy);
    }
}

// ---- full 128-point pass ---------------------------------------------------
// Reg i holds element (c + 8i); after fwd, reg p holds k = BR4(p) + 16*br3(c).
// t128p is the PERMUTED twiddle table: t128p[8p+c] = W128^(c*BR4(p)).
// Read pattern 8p+c: 8 consecutive float2 per p -> 8 distinct banks, each
// address broadcast to 8 lanes -> conflict-free.
__device__ __forceinline__ void pass_fwd(float2 v[16], int c, float2 fA,
                                         const float2* t128p) {
    fft16_fwd(v);
    #pragma unroll
    for (int p = 0; p < 16; p++)
        v[p] = cmul(v[p], t128p[8 * p + c]);
    cross8_fwd(v, c, fA);
}
__device__ __forceinline__ void pass_inv(float2 v[16], int c, float2 fA,
                                         const float2* t128p) {
    cross8_inv(v, c, fA);
    #pragma unroll
    for (int p = 0; p < 16; p++) {
        float2 w = t128p[8 * p + c];
        v[p] = cmul(v[p], make_float2(w.x, -w.y));
    }
    fft16_inv(v);
}

// XOR swizzle for T1 buffer ([kw][r], no padding): col' = col ^ sw1(row)
__device__ __forceinline__ int sw1(int row) {
    return ((row ^ (row >> 4)) & 1) << 3;
}

// ---- main kernel: one block (1024 thr) per scan position -------------------
// No __launch_bounds__ (its waves-per-eu metadata overrode the attribute in
// round 4 -> allocator targeted 8 waves/EU, 64 VGPR, spilled to scratch:
// FETCH 0.59->2.75GB). amdgpu_waves_per_eu(4,4) pins exactly 4 waves/EU
// (the 133KB LDS caps at 1 block/CU = 16 waves anyway) -> 128-VGPR budget.
// Persistent state also trimmed to ~56 VGPRs (prop y-factor moved to a
// permuted LDS table) so even a 64-VGPR allocation cannot spill.
__global__ void
__attribute__((amdgpu_flat_work_group_size(1024, 1024)))
__attribute__((amdgpu_waves_per_eu(4, 4)))
multislice_kernel(const float* __restrict__ probe_re,
                  const float* __restrict__ probe_im,
                  const float* __restrict__ obj_re,
                  const float* __restrict__ obj_im,
                  const int*   __restrict__ positions,
                  float*       __restrict__ out)
{
    __shared__ float2 LT[NPIX];      // 131072 B swizzled transpose buffer
    __shared__ float2 t128p[128];    // permuted W128 twiddle: [8p+c]
    __shared__ float2 pytp[128];     // permuted prop y-factor * 1/16384: [8p+c]

    const int t  = threadIdx.x;
    const int g  = t >> 3;                        // row / column-index [0,128)
    const int c  = t & 7;                         // sub-index in 128-FFT
    const int rc = ((c & 1) << 2) | (c & 2) | ((c & 4) >> 2);   // br3(c)
    const int n  = blockIdx.x;
    const int Y0 = positions[2 * n];
    const int X0 = positions[2 * n + 1];

    if (t < 128) {
        int p_ = t >> 3, c_ = t & 7;
        int rc_ = ((c_ & 1) << 2) | (c_ & 2) | ((c_ & 4) >> 2);
        // twiddle W128^(c*BR4(p)) stored at [8p+c]
        float ang = -2.0f * 3.14159265358979323846f
                    * (float)(c_ * BR4(p_)) / 128.0f;
        float s, cc; __sincosf(ang, &s, &cc);
        t128p[t] = make_float2(cc, s);
        // prop y-factor for kh = BR4(p)+16*br3(c), stored at [8p+c]
        int kh = BR4(p_) + 16 * rc_;
        float fy = (float)(kh < 64 ? kh : kh - 128) * (1.0f / 25.6f);
        float ph = -0.15707963267948966f * fy * fy;
        float ps, pcs; __sincosf(ph, &ps, &pcs);
        pytp[t] = make_float2(pcs * (1.0f / 16384.0f), ps * (1.0f / 16384.0f));
    }
    const float2 fA = make_float2(FA_RE[c], FA_IM[c]);
    float fx = (float)(g < 64 ? g : g - 128) * (1.0f / 25.6f);
    float phx = -0.15707963267948966f * fx * fx;
    float pxs, pxc; __sincosf(phx, &pxs, &pxc);
    const float2 px = make_float2(pxc, pxs);
    __syncthreads();

    float acc[16];
    #pragma unroll
    for (int p = 0; p < 16; p++) acc[p] = 0.0f;

    float2 v[16];

    for (int m = 0; m < NMODES; m++) {
        __syncthreads();   // protect LT reuse across modes
        #pragma unroll
        for (int i = 0; i < 16; i++) {           // ex = probe[m]*patch(slice0)
            int w  = c + 8 * i;
            int pi = m * NPIX + g * 128 + w;
            float2 pr = make_float2(probe_re[pi], probe_im[pi]);
            int oi = (Y0 + g) * OBJW + X0 + w;
            float2 ob = make_float2(obj_re[oi], obj_im[oi]);
            v[i] = cmul(pr, ob);
        }

        for (int s = 1; s < NSLICES; s++) {
            pass_fwd(v, c, fA, t128p);           // Fw
            #pragma unroll                       // T1 write [kw][r=g]
            for (int p = 0; p < 16; p++) {
                int kw = BR4(p) + 16 * rc;
                LT[kw * 128 + (g ^ sw1(kw))] = v[p];
            }
            __syncthreads();
            #pragma unroll                       // T1 read -> C-state
            for (int i = 0; i < 16; i++)
                v[i] = LT[g * 128 + ((c + 8 * i) ^ sw1(g))];
            __syncthreads();
            pass_fwd(v, c, fA, t128p);           // Fh
            #pragma unroll                       // * prop: (py from LDS)*px
            for (int p = 0; p < 16; p++) {
                float2 pp = cmul(pytp[8 * p + c], px);
                v[p] = cmul(v[p], pp);
            }
            pass_inv(v, c, fA, t128p);           // iFh
            #pragma unroll                       // T2 write [r][kw=g]
            for (int i = 0; i < 16; i++) {
                int r = c + 8 * i;
                int col = g ^ ((r & 7) << 1) ^ ((g >> 4) & 1);
                LT[r * 128 + col] = v[i];
            }
            __syncthreads();
            #pragma unroll                       // T2 read -> R-state(perm)
            for (int p = 0; p < 16; p++) {
                int kw = BR4(p) + 16 * rc;
                int col = kw ^ ((g & 7) << 1) ^ ((kw >> 4) & 1);
                v[p] = LT[g * 128 + col];
            }
            __syncthreads();
            pass_inv(v, c, fA, t128p);           // iFw
            #pragma unroll                       // * patch(slice s)
            for (int i = 0; i < 16; i++) {
                int w  = c + 8 * i;
                int oi = (s * OBJW + Y0 + g) * OBJW + X0 + w;
                float2 ob = make_float2(obj_re[oi], obj_im[oi]);
                v[i] = cmul(v[i], ob);
            }
        }

        // final FFT2: Fw, T1, Fh, accumulate |.|^2
        pass_fwd(v, c, fA, t128p);
        #pragma unroll
        for (int p = 0; p < 16; p++) {
            int kw = BR4(p) + 16 * rc;
            LT[kw * 128 + (g ^ sw1(kw))] = v[p];
        }
        __syncthreads();
        #pragma unroll
        for (int i = 0; i < 16; i++)
            v[i] = LT[g * 128 + ((c + 8 * i) ^ sw1(g))];
        pass_fwd(v, c, fA, t128p);
        #pragma unroll
        for (int p = 0; p < 16; p++)
            acc[p] += v[p].x * v[p].x + v[p].y * v[p].y;
    }

    // store with fftshift: (kh,kw) -> (kh^64, kw^64); kh=BR4(p)+16rc, kw=g
    const long long base = (long long)n * NPIX;
    #pragma unroll
    for (int p = 0; p < 16; p++) {
        int kh = BR4(p) + 16 * rc;
        out[base + (long long)(((kh ^ 64) << 7) + (g ^ 64))] = acc[p];
    }
}

extern "C" void kernel_launch(void* const* d_in, const int* in_sizes, int n_in,
                              void* d_out, int out_size, void* d_ws, size_t ws_size,
                              hipStream_t stream) {
    const float* probe_re = (const float*)d_in[0];
    const float* probe_im = (const float*)d_in[1];
    const float* obj_re   = (const float*)d_in[2];
    const float* obj_im   = (const float*)d_in[3];
    const int*   pos      = (const int*)d_in[4];
    float* out = (float*)d_out;

    const int N = out_size / NPIX;   // 512 positions
    multislice_kernel<<<dim3(N), dim3(NT), 0, stream>>>(
        probe_re, probe_im, obj_re, obj_im, pos, out);
}